// Round 18
// baseline (107.696 us; speedup 1.0000x reference)
//
#include <hip/hip_runtime.h>
#include <math.h>

#define NN 50000
#define NE 800000
#define FIN 128
#define NC 10
#define NEG 0.2f
#define LOG2E 1.4426950408889634f

#define NB 196        // coarse buckets = ceil(NN/256), bucket = dst>>8
#define CHUNK 4096    // edges per pass1 block
#define P1B ((NE + CHUNK - 1) / CHUNK)   // 196
#define CAP 5120      // LDS capacity for one bucket in pass2
#define GMT ((NN + 127) / 128)           // 391 mfma-gemm tiles (128 nodes, both W)
#define GH1 196       // gemm1 tiles in kernel A
#define GH2 (GMT - GH1)                  // 195 gemm1 tiles in kernel B
#define LBW 200       // lbmat row stride
#define WPAD 136      // Wt row stride in f16 (272B: 16B-aligned, bank-balanced)

typedef unsigned int uint;
typedef _Float16 h2 __attribute__((ext_vector_type(2)));
typedef _Float16 h8 __attribute__((ext_vector_type(8)));
typedef float f32x4 __attribute__((ext_vector_type(4)));
typedef __fp16 hb2 __attribute__((ext_vector_type(2)));
union U2H { uint u; h2 h; };
union U4H8 { uint4 u; h8 h; };

__device__ __forceinline__ uint pkrtz_u(float a, float b) {
    union { hb2 f; uint u; } r;
    r.f = __builtin_amdgcn_cvt_pkrtz(a, b);
    return r.u;
}

__device__ __forceinline__ float dot2f(h2 a, h2 b, float c) {
#if __has_builtin(__builtin_amdgcn_fdot2)
    return __builtin_amdgcn_fdot2(a, b, c, false);
#else
    return fmaf((float)a.x, (float)b.x, fmaf((float)a.y, (float)b.y, c));
#endif
}

// raw v_exp_f32 (inputs bounded; skip OCML fixups)
__device__ __forceinline__ float fexp2(float x) {
#if __has_builtin(__builtin_amdgcn_exp2f)
    return __builtin_amdgcn_exp2f(x);
#else
    return exp2f(x);
#endif
}

// load u32 at base + 32-bit byte offset
__device__ __forceinline__ uint ld_off(const uint* __restrict__ base, uint byteoff) {
    return *(const uint*)((const char*)base + (size_t)byteoff);
}

__device__ __forceinline__ h2 lrelu2(h2 v) {
    return __builtin_elementwise_max(v, v * (_Float16)0.2f);
}

template<int CTRL>
__device__ __forceinline__ float dpp_add(float x) {
    int y = __builtin_amdgcn_update_dpp(0, __float_as_int(x), CTRL, 0xF, 0xF, true);
    return x + __int_as_float(y);
}
__device__ __forceinline__ float red8(float t) {
    t = dpp_add<0xB1>(t);
    t = dpp_add<0x4E>(t);
    t = dpp_add<0x141>(t);
    return t;
}

__device__ __forceinline__ int excl_scan256(int v, int* sc) {
    const int t = threadIdx.x;
    sc[t] = v;
    __syncthreads();
    for (int o = 1; o < 256; o <<= 1) {
        int u = (t >= o) ? sc[t - o] : 0;
        __syncthreads();
        sc[t] += u;
        __syncthreads();
    }
    return sc[t] - v;
}

// ---------------- pass1: per-chunk bucket-sort (deterministic layout) ----------------

__device__ void pass1_body(const int* __restrict__ ei, uint* __restrict__ temp,
                           int* __restrict__ lbmat, char* smraw) {
    uint* pk = (uint*)smraw;                  // 16384 B [4096]
    int* h   = (int*)(smraw + 16384);         // 1024
    int* h2_ = (int*)(smraw + 17408);         // 1024
    int* sc  = (int*)(smraw + 18432);         // 1024
    const int t = threadIdx.x;
    const int B = blockIdx.x;
    const int e0 = B * CHUNK;
    const int cnt = min(CHUNK, NE - e0);

    h[t] = 0; h2_[t] = 0;
    __syncthreads();
    for (int i = t; i < cnt; i += 256) {
        int d = ei[NE + e0 + i];
        atomicAdd(&h[d >> 8], 1);
    }
    __syncthreads();
    const int hv = h[t];
    const int ex = excl_scan256(hv, sc);
    if (t < NB) lbmat[B * LBW + t] = ex;
    if (t == NB - 1) lbmat[B * LBW + NB] = ex + hv;
    h2_[t] = ex;
    __syncthreads();
    for (int i = t; i < cnt; i += 256) {
        int s = ei[e0 + i];
        int d = ei[NE + e0 + i];
        int b = d >> 8;
        int pos = atomicAdd(&h2_[b], 1);
        pk[pos] = ((uint)s << 8) | ((uint)d & 255u);
    }
    __syncthreads();
    for (int i = t; i < cnt; i += 256) temp[B * CHUNK + i] = pk[i];
}

// ---------------- pass2 body: pull-based per-bucket CSR (no global atomics) ----------------

__device__ void pass2_body(const uint* __restrict__ temp,
                           const int* __restrict__ lbmat,
                           int* __restrict__ rowptr,
                           int* __restrict__ deg,
                           int* __restrict__ csr_src,
                           int b, char* smraw) {
    uint* P   = (uint*)smraw;                 // 20480 B [CAP]
    int* nh   = (int*)(smraw + 20480);        // 1024
    int* nbx  = (int*)(smraw + 21504);        // 1024
    int* ncur = (int*)(smraw + 22528);        // 1024
    int* sc   = (int*)(smraw + 23552);        // 1024
    const int t = threadIdx.x;

    int lbv = 0, len = 0;
    if (t < P1B) {
        lbv = lbmat[t * LBW + b];
        len = lbmat[t * LBW + b + 1] - lbv;
    }
    const int colstart = excl_scan256(len, sc);
    __syncthreads();
    const int cnt = sc[255];
    __syncthreads();
    (void)excl_scan256(lbv, sc);
    __syncthreads();
    const int csrbase = sc[255];
    __syncthreads();
    nh[t] = 0; ncur[t] = 0;
    __syncthreads();
    if (t < P1B) {
        const uint* src = temp + t * CHUNK + lbv;
        int i = 0;
        for (; i + 8 <= len; i += 8) {        // batch-8: 8 loads in flight
            uint r0 = src[i + 0], r1 = src[i + 1], r2 = src[i + 2], r3 = src[i + 3];
            uint r4 = src[i + 4], r5 = src[i + 5], r6 = src[i + 6], r7 = src[i + 7];
            P[colstart + i + 0] = r0; P[colstart + i + 1] = r1;
            P[colstart + i + 2] = r2; P[colstart + i + 3] = r3;
            P[colstart + i + 4] = r4; P[colstart + i + 5] = r5;
            P[colstart + i + 6] = r6; P[colstart + i + 7] = r7;
        }
        for (; i < len; ++i) P[colstart + i] = src[i];
    }
    __syncthreads();
    for (int i = t; i < cnt; i += 256) atomicAdd(&nh[P[i] & 255u], 1);
    __syncthreads();
    const int c = nh[t];
    const int nb_ex = excl_scan256(c, sc);
    nbx[t] = nb_ex;
    const int gnode = b * 256 + t;
    if (gnode < NN) { rowptr[gnode] = csrbase + nb_ex; deg[gnode] = c; }
    __syncthreads();
    for (int i = t; i < cnt; i += 256) {
        uint v = P[i];
        int l = (int)(v & 255u);
        int r = atomicAdd(&ncur[l], 1);
        csr_src[csrbase + nbx[l] + r] = (int)(v >> 8);
    }
}

// ---------------- gemm1 MFMA body: 128 nodes x 128 cols per block ----------------

__device__ void gemm1_body(const float* __restrict__ x,
                           const float* __restrict__ W1l,
                           const float* __restrict__ W1r,
                           _Float16* __restrict__ xlh,
                           _Float16* __restrict__ xrh,
                           int n0, char* smraw) {
    _Float16 (*WtL)[WPAD] = (_Float16(*)[WPAD])smraw;
    _Float16 (*WtR)[WPAD] = (_Float16(*)[WPAD])(smraw + 64 * WPAD * 2);
    const int t = threadIdx.x;

    for (int i = t; i < FIN * 64; i += 256) {   // stage both W transposed as f16
        int k = i >> 6, c = i & 63;
        WtL[c][k] = (_Float16)W1l[i];
        WtR[c][k] = (_Float16)W1r[i];
    }
    __syncthreads();

    const int lane = t & 63;
    const int wid = t >> 6;
    const int col16 = lane & 15;
    const int kgrp = (lane >> 4) * 8;

    f32x4 acc[2][8] = {};
    for (int kk = 0; kk < FIN; kk += 32) {
        U4H8 a[2];
#pragma unroll
        for (int s = 0; s < 2; ++s) {
            int arow = n0 + s * 64 + wid * 16 + col16;
            if (arow < NN) {
                const float4* xp = (const float4*)(x + (size_t)arow * FIN + kk + kgrp);
                float4 v0 = xp[0], v1 = xp[1];
                a[s].u = make_uint4(pkrtz_u(v0.x, v0.y), pkrtz_u(v0.z, v0.w),
                                    pkrtz_u(v1.x, v1.y), pkrtz_u(v1.z, v1.w));
            } else {
                a[s].u = make_uint4(0u, 0u, 0u, 0u);
            }
        }
        const int kof = kk + kgrp;
#pragma unroll
        for (int ct = 0; ct < 4; ++ct) {
            U4H8 b; b.u = *(const uint4*)&WtL[ct * 16 + col16][kof];
            acc[0][ct] = __builtin_amdgcn_mfma_f32_16x16x32_f16(a[0].h, b.h, acc[0][ct], 0, 0, 0);
            acc[1][ct] = __builtin_amdgcn_mfma_f32_16x16x32_f16(a[1].h, b.h, acc[1][ct], 0, 0, 0);
        }
#pragma unroll
        for (int ct = 0; ct < 4; ++ct) {
            U4H8 b; b.u = *(const uint4*)&WtR[ct * 16 + col16][kof];
            acc[0][4 + ct] = __builtin_amdgcn_mfma_f32_16x16x32_f16(a[0].h, b.h, acc[0][4 + ct], 0, 0, 0);
            acc[1][4 + ct] = __builtin_amdgcn_mfma_f32_16x16x32_f16(a[1].h, b.h, acc[1][4 + ct], 0, 0, 0);
        }
    }
#pragma unroll
    for (int s = 0; s < 2; ++s) {
        const int crow0 = n0 + s * 64 + wid * 16 + (lane >> 4) * 4;
#pragma unroll
        for (int ct = 0; ct < 8; ++ct) {
            _Float16* __restrict__ op = (ct < 4) ? xlh : xrh;
            const int col = (ct & 3) * 16 + col16;
#pragma unroll
            for (int r = 0; r < 4; ++r) {
                int node = crow0 + r;
                if (node < NN) op[(size_t)node * 64 + col] = (_Float16)acc[s][ct][r];
            }
        }
    }
}

// ---------------- kernel A: pass1 || gemm1 tiles 0..GH1-1 ----------------

__global__ __launch_bounds__(256) void k_fusedA(const float* __restrict__ x,
                                                const int* __restrict__ ei,
                                                const float* __restrict__ W1l,
                                                const float* __restrict__ W1r,
                                                _Float16* __restrict__ xlh,
                                                _Float16* __restrict__ xrh,
                                                uint* __restrict__ temp,
                                                int* __restrict__ lbmat) {
    __shared__ __align__(16) char smraw[64 * WPAD * 2 * 2];   // 34816 B
    if (blockIdx.x < P1B) {
        pass1_body(ei, temp, lbmat, smraw);
    } else {
        int g = blockIdx.x - P1B;
        gemm1_body(x, W1l, W1r, xlh, xrh, g * 128, smraw);
    }
}

// ---------------- kernel B: pass2 || gemm1 tiles GH1..GMT-1 ----------------

__global__ __launch_bounds__(256) void k_fusedB(const float* __restrict__ x,
                                                const float* __restrict__ W1l,
                                                const float* __restrict__ W1r,
                                                _Float16* __restrict__ xlh,
                                                _Float16* __restrict__ xrh,
                                                const uint* __restrict__ temp,
                                                const int* __restrict__ lbmat,
                                                int* __restrict__ rowptr,
                                                int* __restrict__ deg,
                                                int* __restrict__ csr_src) {
    __shared__ __align__(16) char smraw[64 * WPAD * 2 * 2];   // 34816 B (>= pass2's 24576)
    if (blockIdx.x < NB) {
        pass2_body(temp, lbmat, rowptr, deg, csr_src, blockIdx.x, smraw);
    } else {
        int g = GH1 + (blockIdx.x - NB);
        gemm1_body(x, W1l, W1r, xlh, xrh, g * 128, smraw);
    }
}

// ---------------- layer 1 aggregate: masked batch-4, hw exp2, voffset gathers (R15) ----------------

__global__ __launch_bounds__(256) void k_agg1(const uint* __restrict__ xlh2,
                                              const uint* __restrict__ xrh2,
                                              const int* __restrict__ rowptr,
                                              const int* __restrict__ deg,
                                              const int* __restrict__ csr_src,
                                              const float* __restrict__ att1,
                                              const float* __restrict__ b1,
                                              uint* __restrict__ hbh2) {
    const int node = blockIdx.x * 4 + (threadIdx.x >> 6);
    if (node >= NN) return;
    const int lane = threadIdx.x & 63;
    const int fl = lane & 31;
    const uint fl4 = (uint)fl * 4u;
    const int hid = lane >> 5;
    float2 av = *(const float2*)&att1[2 * fl];
    U2H att; att.u = pkrtz_u(av.x * LOG2E, av.y * LOG2E);
    U2H xrf; xrf.u = xrh2[(size_t)node * 32 + fl];
    const int start = rowptr[node];
    const int dg = deg[node];
    const int permbase = (lane & 32) >> 3;

    float denom = 0.f, acc0 = 0.f, acc1 = 0.f;
    for (int base = 0; base < dg; base += 64) {
        int idx = base + lane;
        uint srcb = (idx < dg) ? ((uint)csr_src[start + idx] << 7) : 0u;
        int rem = dg - base; if (rem > 64) rem = 64;
        int iters = (rem + 1) >> 1;
        int thr = (rem - hid + 1) >> 1;
        for (int jj = 0; jj < iters; jj += 4) {
            uint o0 = (uint)__builtin_amdgcn_ds_bpermute((jj + 0) * 8 + permbase, (int)srcb) + fl4;
            uint o1 = (uint)__builtin_amdgcn_ds_bpermute((jj + 1) * 8 + permbase, (int)srcb) + fl4;
            uint o2 = (uint)__builtin_amdgcn_ds_bpermute((jj + 2) * 8 + permbase, (int)srcb) + fl4;
            uint o3 = (uint)__builtin_amdgcn_ds_bpermute((jj + 3) * 8 + permbase, (int)srcb) + fl4;
            U2H v0; v0.u = ld_off(xlh2, o0);
            U2H v1; v1.u = ld_off(xlh2, o1);
            U2H v2; v2.u = ld_off(xlh2, o2);
            U2H v3; v3.u = ld_off(xlh2, o3);
            float t0 = red8(dot2f(lrelu2(v0.h + xrf.h), att.h, 0.f));
            float t1 = red8(dot2f(lrelu2(v1.h + xrf.h), att.h, 0.f));
            float t2 = red8(dot2f(lrelu2(v2.h + xrf.h), att.h, 0.f));
            float t3 = red8(dot2f(lrelu2(v3.h + xrf.h), att.h, 0.f));
            float e0 = (jj + 0 < thr) ? fexp2(t0) : 0.f;
            float e1 = (jj + 1 < thr) ? fexp2(t1) : 0.f;
            float e2 = (jj + 2 < thr) ? fexp2(t2) : 0.f;
            float e3 = (jj + 3 < thr) ? fexp2(t3) : 0.f;
            denom += (e0 + e1) + (e2 + e3);
            acc0 = fmaf(e0, (float)v0.h.x, acc0);
            acc0 = fmaf(e1, (float)v1.h.x, acc0);
            acc0 = fmaf(e2, (float)v2.h.x, acc0);
            acc0 = fmaf(e3, (float)v3.h.x, acc0);
            acc1 = fmaf(e0, (float)v0.h.y, acc1);
            acc1 = fmaf(e1, (float)v1.h.y, acc1);
            acc1 = fmaf(e2, (float)v2.h.y, acc1);
            acc1 = fmaf(e3, (float)v3.h.y, acc1);
        }
    }
    denom += __shfl_xor(denom, 32);
    acc0  += __shfl_xor(acc0, 32);
    acc1  += __shfl_xor(acc1, 32);
    if (lane < 32) {
        float r = (dg > 0) ? (1.0f / denom) : 0.f;
        float2 bv = *(const float2*)&b1[2 * fl];
        float o0 = fmaf(acc0, r, bv.x);
        float o1 = fmaf(acc1, r, bv.y);
        o0 = o0 > 0.f ? o0 : expm1f(o0);
        o1 = o1 > 0.f ? o1 : expm1f(o1);
        hbh2[(size_t)node * 32 + fl] = pkrtz_u(o0, o1);
    }
}

// ---------------- layer 2 GEMM: node per thread, packed half2 outputs ----------------

__global__ __launch_bounds__(256) void k_gemm2(const uint* __restrict__ hbh2,
                                               const float* __restrict__ W2l,
                                               const float* __restrict__ W2r,
                                               uint* __restrict__ xl2h,
                                               uint* __restrict__ xr2h) {
    int n = blockIdx.x * 256 + threadIdx.x;
    if (n >= NN) return;
    float al[NC] = {}, ar[NC] = {};
    const uint4* hr4 = (const uint4*)(hbh2 + (size_t)n * 32);
#pragma unroll
    for (int q = 0; q < 8; ++q) {
        uint4 qq = hr4[q];
        uint uu[4] = {qq.x, qq.y, qq.z, qq.w};
#pragma unroll
        for (int j = 0; j < 4; ++j) {
            U2H hh; hh.u = uu[j];
            float f0 = (float)hh.h.x, f1 = (float)hh.h.y;
            int k = q * 8 + j * 2;
            const float* wl0 = W2l + k * NC;
            const float* wr0 = W2r + k * NC;
#pragma unroll
            for (int c = 0; c < NC; ++c) {
                al[c] = fmaf(f0, wl0[c], fmaf(f1, wl0[NC + c], al[c]));
                ar[c] = fmaf(f0, wr0[c], fmaf(f1, wr0[NC + c], ar[c]));
            }
        }
    }
    uint p0 = pkrtz_u(al[0], al[1]);
    uint p1 = pkrtz_u(al[2], al[3]);
    uint p2 = pkrtz_u(al[4], al[5]);
    uint p3 = pkrtz_u(al[6], al[7]);
    uint p4 = pkrtz_u(al[8], al[9]);
    *(uint4*)&xl2h[(size_t)n * 8]     = make_uint4(p0, p1, p2, p3);
    *(uint4*)&xl2h[(size_t)n * 8 + 4] = make_uint4(p4, 0u, 0u, 0u);
    p0 = pkrtz_u(ar[0], ar[1]);
    p1 = pkrtz_u(ar[2], ar[3]);
    p2 = pkrtz_u(ar[4], ar[5]);
    p3 = pkrtz_u(ar[6], ar[7]);
    p4 = pkrtz_u(ar[8], ar[9]);
    *(uint4*)&xr2h[(size_t)n * 8]     = make_uint4(p0, p1, p2, p3);
    *(uint4*)&xr2h[(size_t)n * 8 + 4] = make_uint4(p4, 0u, 0u, 0u);
}

// ---------------- layer 2 aggregate: masked batch-4, hw exp2, voffset gathers (R15) ----------------

__global__ __launch_bounds__(256) void k_agg2(const uint* __restrict__ xl2h,
                                              const uint* __restrict__ xr2h,
                                              const int* __restrict__ rowptr,
                                              const int* __restrict__ deg,
                                              const int* __restrict__ csr_src,
                                              const float* __restrict__ att2,
                                              const float* __restrict__ b2,
                                              float* __restrict__ out) {
    const int node = blockIdx.x * 4 + (threadIdx.x >> 6);
    if (node >= NN) return;
    const int lane = threadIdx.x & 63;
    const int fp = lane & 7;
    const uint fp4 = (uint)fp * 4u;
    const int eg = lane >> 3;
    U2H att;
    if (fp < 5) {
        float2 av = *(const float2*)&att2[2 * fp];
        att.u = pkrtz_u(av.x * LOG2E, av.y * LOG2E);
    } else {
        att.u = 0;
    }
    U2H xrf; xrf.u = xr2h[(size_t)node * 8 + fp];
    const int start = rowptr[node];
    const int dg = deg[node];
    const int permbase = eg * 4;

    float denom = 0.f, acc0 = 0.f, acc1 = 0.f;
    for (int base = 0; base < dg; base += 64) {
        int idx = base + lane;
        uint srcb = (idx < dg) ? ((uint)csr_src[start + idx] << 5) : 0u;
        int rem = dg - base; if (rem > 64) rem = 64;
        int iters = (rem + 7) >> 3;
        int thr = (rem - eg + 7) >> 3;
        for (int jj = 0; jj < iters; jj += 4) {
            uint o[4]; U2H v[4];
#pragma unroll
            for (int k = 0; k < 4; ++k)
                o[k] = (uint)__builtin_amdgcn_ds_bpermute((jj + k) * 32 + permbase, (int)srcb) + fp4;
#pragma unroll
            for (int k = 0; k < 4; ++k)
                v[k].u = ld_off(xl2h, o[k]);
#pragma unroll
            for (int k = 0; k < 4; ++k) {
                float tl = red8(dot2f(lrelu2(v[k].h + xrf.h), att.h, 0.f));
                float e = (jj + k < thr) ? fexp2(tl) : 0.f;
                denom += e;
                acc0 = fmaf(e, (float)v[k].h.x, acc0);
                acc1 = fmaf(e, (float)v[k].h.y, acc1);
            }
        }
    }
#pragma unroll
    for (int m = 8; m <= 32; m <<= 1) {
        denom += __shfl_xor(denom, m);
        acc0  += __shfl_xor(acc0, m);
        acc1  += __shfl_xor(acc1, m);
    }
    if (lane < 5) {
        float r = (dg > 0) ? (1.0f / denom) : 0.f;
        float2 o;
        o.x = fmaf(acc0, r, b2[2 * fp]);
        o.y = fmaf(acc1, r, b2[2 * fp + 1]);
        *(float2*)&out[(size_t)node * NC + 2 * fp] = o;
    }
}

// ---------------- launch ----------------

extern "C" void kernel_launch(void* const* d_in, const int* in_sizes, int n_in,
                              void* d_out, int out_size, void* d_ws, size_t ws_size,
                              hipStream_t stream) {
    const float* x    = (const float*)d_in[0];
    const int*   ei   = (const int*)d_in[1];
    const float* W1l  = (const float*)d_in[2];
    const float* W1r  = (const float*)d_in[3];
    const float* att1 = (const float*)d_in[4];
    const float* b1   = (const float*)d_in[5];
    const float* W2l  = (const float*)d_in[6];
    const float* W2r  = (const float*)d_in[7];
    const float* att2 = (const float*)d_in[8];
    const float* b2   = (const float*)d_in[9];
    float* out = (float*)d_out;

    char* w = (char*)d_ws;
    size_t off = 0;
    auto alloc = [&](size_t bytes) -> void* {
        void* p = w + off;
        off = (off + bytes + 255) & ~(size_t)255;
        return p;
    };
    uint* xlh2   = (uint*)alloc((size_t)NN * 32 * 4);
    uint* xrh2   = (uint*)alloc((size_t)NN * 32 * 4);
    uint* hbh2   = (uint*)alloc((size_t)NN * 32 * 4);
    uint* xl2h   = (uint*)alloc((size_t)NN * 8 * 4);
    uint* xr2h   = (uint*)alloc((size_t)NN * 8 * 4);
    uint* temp   = (uint*)alloc((size_t)P1B * CHUNK * 4);
    int*  lbmat  = (int*)alloc((size_t)P1B * LBW * 4);
    int*  rowptr = (int*)alloc((size_t)NN * 4);
    int*  deg    = (int*)alloc((size_t)NN * 4);
    int*  csr_src = (int*)alloc((size_t)(NE + 64) * 4);

    k_fusedA<<<P1B + GH1, 256, 0, stream>>>(x, ei, W1l, W1r,
                                            (_Float16*)xlh2, (_Float16*)xrh2,
                                            temp, lbmat);
    k_fusedB<<<NB + GH2, 256, 0, stream>>>(x, W1l, W1r,
                                           (_Float16*)xlh2, (_Float16*)xrh2,
                                           temp, lbmat, rowptr, deg, csr_src);
    k_agg1<<<(NN + 3) / 4, 256, 0, stream>>>(xlh2, xrh2, rowptr, deg, csr_src, att1, b1, hbh2);
    k_gemm2<<<(NN + 255) / 256, 256, 0, stream>>>(hbh2, W2l, W2r, xl2h, xr2h);
    k_agg2<<<(NN + 3) / 4, 256, 0, stream>>>(xl2h, xr2h, rowptr, deg, csr_src, att2, b2, out);
}

// Round 19
// 92.537 us; speedup vs baseline: 1.1638x; 1.1638x over previous
//
#include <hip/hip_runtime.h>
#include <math.h>

#define NN 50000
#define NE 800000
#define FIN 128
#define NC 10
#define NEG 0.2f
#define LOG2E 1.4426950408889634f

#define NB 196        // coarse buckets = ceil(NN/256), bucket = dst>>8
#define CHUNK 4096    // edges per pass1 block
#define P1B ((NE + CHUNK - 1) / CHUNK)   // 196
#define CAP 5120      // LDS capacity for one bucket in pass2
#define GMT ((NN + 63) / 64)             // 782 mfma-gemm tiles (64 nodes, both W)
#define LBW 200       // lbmat row stride
#define WPAD 136      // Wt row stride in f16 (272B: 16B-aligned, bank-balanced)

typedef unsigned int uint;
typedef _Float16 h2 __attribute__((ext_vector_type(2)));
typedef _Float16 h8 __attribute__((ext_vector_type(8)));
typedef float f32x4 __attribute__((ext_vector_type(4)));
typedef __fp16 hb2 __attribute__((ext_vector_type(2)));
union U2H { uint u; h2 h; };
union U4H8 { uint4 u; h8 h; };

__device__ __forceinline__ uint pkrtz_u(float a, float b) {
    union { hb2 f; uint u; } r;
    r.f = __builtin_amdgcn_cvt_pkrtz(a, b);
    return r.u;
}

__device__ __forceinline__ float dot2f(h2 a, h2 b, float c) {
#if __has_builtin(__builtin_amdgcn_fdot2)
    return __builtin_amdgcn_fdot2(a, b, c, false);
#else
    return fmaf((float)a.x, (float)b.x, fmaf((float)a.y, (float)b.y, c));
#endif
}

// raw v_exp_f32 (inputs bounded; skip OCML fixups)
__device__ __forceinline__ float fexp2(float x) {
#if __has_builtin(__builtin_amdgcn_exp2f)
    return __builtin_amdgcn_exp2f(x);
#else
    return exp2f(x);
#endif
}

// load u32 at base + 32-bit byte offset (saddr + voffset form, no 64-bit vadd)
__device__ __forceinline__ uint ld_off(const uint* __restrict__ base, uint byteoff) {
    return *(const uint*)((const char*)base + (size_t)byteoff);
}

__device__ __forceinline__ h2 lrelu2(h2 v) {
    return __builtin_elementwise_max(v, v * (_Float16)0.2f);
}

template<int CTRL>
__device__ __forceinline__ float dpp_add(float x) {
    int y = __builtin_amdgcn_update_dpp(0, __float_as_int(x), CTRL, 0xF, 0xF, true);
    return x + __int_as_float(y);
}
__device__ __forceinline__ float red8(float t) {
    t = dpp_add<0xB1>(t);
    t = dpp_add<0x4E>(t);
    t = dpp_add<0x141>(t);
    return t;
}

__device__ __forceinline__ int excl_scan256(int v, int* sc) {
    const int t = threadIdx.x;
    sc[t] = v;
    __syncthreads();
    for (int o = 1; o < 256; o <<= 1) {
        int u = (t >= o) ? sc[t - o] : 0;
        __syncthreads();
        sc[t] += u;
        __syncthreads();
    }
    return sc[t] - v;
}

// ---------------- fused kernel A: pass1 bucket-sort || gemm1 (MFMA f16) ----------------

__device__ void pass1_body(const int* __restrict__ ei, uint* __restrict__ temp,
                           int* __restrict__ lbmat, char* smraw) {
    uint* pk = (uint*)smraw;                  // 16384 B [4096]
    int* h   = (int*)(smraw + 16384);         // 1024
    int* h2_ = (int*)(smraw + 17408);         // 1024
    int* sc  = (int*)(smraw + 18432);         // 1024
    const int t = threadIdx.x;
    const int B = blockIdx.x;
    const int e0 = B * CHUNK;
    const int cnt = min(CHUNK, NE - e0);

    h[t] = 0; h2_[t] = 0;
    __syncthreads();
    for (int i = t; i < cnt; i += 256) {
        int d = ei[NE + e0 + i];
        atomicAdd(&h[d >> 8], 1);
    }
    __syncthreads();
    const int hv = h[t];
    const int ex = excl_scan256(hv, sc);
    if (t < NB) lbmat[B * LBW + t] = ex;
    if (t == NB - 1) lbmat[B * LBW + NB] = ex + hv;
    h2_[t] = ex;
    __syncthreads();
    for (int i = t; i < cnt; i += 256) {
        int s = ei[e0 + i];
        int d = ei[NE + e0 + i];
        int b = d >> 8;
        int pos = atomicAdd(&h2_[b], 1);
        pk[pos] = ((uint)s << 8) | ((uint)d & 255u);
    }
    __syncthreads();
    for (int i = t; i < cnt; i += 256) temp[B * CHUNK + i] = pk[i];
}

// gemm1 MFMA: block = 64 nodes x 128 cols (both W sides). 4 waves x 16 nodes.
__device__ void gemm1_body(const float* __restrict__ x,
                           const float* __restrict__ W1l,
                           const float* __restrict__ W1r,
                           _Float16* __restrict__ xlh,
                           _Float16* __restrict__ xrh,
                           int n0, char* smraw) {
    _Float16 (*WtL)[WPAD] = (_Float16(*)[WPAD])smraw;
    _Float16 (*WtR)[WPAD] = (_Float16(*)[WPAD])(smraw + 64 * WPAD * 2);
    const int t = threadIdx.x;

    for (int i = t; i < FIN * 64; i += 256) {   // stage both W transposed as f16
        int k = i >> 6, c = i & 63;
        WtL[c][k] = (_Float16)W1l[i];
        WtR[c][k] = (_Float16)W1r[i];
    }
    __syncthreads();

    const int lane = t & 63;
    const int n0w = n0 + (t >> 6) * 16;
    const int arow = n0w + (lane & 15);
    const int kgrp = (lane >> 4) * 8;
    const int col16 = lane & 15;

    f32x4 acc[8] = {};
    for (int kk = 0; kk < FIN; kk += 32) {
        U4H8 a;
        if (arow < NN) {
            const float4* xp = (const float4*)(x + (size_t)arow * FIN + kk + kgrp);
            float4 v0 = xp[0], v1 = xp[1];
            a.u = make_uint4(pkrtz_u(v0.x, v0.y), pkrtz_u(v0.z, v0.w),
                             pkrtz_u(v1.x, v1.y), pkrtz_u(v1.z, v1.w));
        } else {
            a.u = make_uint4(0u, 0u, 0u, 0u);
        }
        const int kof = kk + kgrp;
#pragma unroll
        for (int ct = 0; ct < 4; ++ct) {
            U4H8 b; b.u = *(const uint4*)&WtL[ct * 16 + col16][kof];
            acc[ct] = __builtin_amdgcn_mfma_f32_16x16x32_f16(a.h, b.h, acc[ct], 0, 0, 0);
        }
#pragma unroll
        for (int ct = 0; ct < 4; ++ct) {
            U4H8 b; b.u = *(const uint4*)&WtR[ct * 16 + col16][kof];
            acc[4 + ct] = __builtin_amdgcn_mfma_f32_16x16x32_f16(a.h, b.h, acc[4 + ct], 0, 0, 0);
        }
    }
    const int crow0 = n0w + (lane >> 4) * 4;
#pragma unroll
    for (int ct = 0; ct < 8; ++ct) {
        _Float16* __restrict__ op = (ct < 4) ? xlh : xrh;
        const int col = (ct & 3) * 16 + col16;
#pragma unroll
        for (int r = 0; r < 4; ++r) {
            int node = crow0 + r;
            if (node < NN) op[(size_t)node * 64 + col] = (_Float16)acc[ct][r];
        }
    }
}

__global__ __launch_bounds__(256) void k_fusedA(const float* __restrict__ x,
                                                const int* __restrict__ ei,
                                                const float* __restrict__ W1l,
                                                const float* __restrict__ W1r,
                                                _Float16* __restrict__ xlh,
                                                _Float16* __restrict__ xrh,
                                                uint* __restrict__ temp,
                                                int* __restrict__ lbmat) {
    __shared__ __align__(16) char smraw[64 * WPAD * 2 * 2];   // 34816 B
    if (blockIdx.x < P1B) {
        pass1_body(ei, temp, lbmat, smraw);
    } else {
        int g = blockIdx.x - P1B;
        gemm1_body(x, W1l, W1r, xlh, xrh, g * 64, smraw);
    }
}

// ---------------- pass2: pull-based per-bucket CSR (no global atomics) ----------------

__global__ __launch_bounds__(256) void k_pass2(const uint* __restrict__ temp,
                                               const int* __restrict__ lbmat,
                                               int* __restrict__ rowptr,
                                               int* __restrict__ deg,
                                               int* __restrict__ csr_src) {
    __shared__ uint P[CAP];
    __shared__ int nh[256], nbx[256], ncur[256], sc[256];
    const int t = threadIdx.x;
    const int b = blockIdx.x;

    int lbv = 0, len = 0;
    if (t < P1B) {
        lbv = lbmat[t * LBW + b];
        len = lbmat[t * LBW + b + 1] - lbv;
    }
    const int colstart = excl_scan256(len, sc);
    __syncthreads();
    const int cnt = sc[255];
    __syncthreads();
    (void)excl_scan256(lbv, sc);
    __syncthreads();
    const int csrbase = sc[255];
    __syncthreads();
    nh[t] = 0; ncur[t] = 0;
    __syncthreads();
    if (t < P1B) {
        const uint* src = temp + t * CHUNK + lbv;
        for (int i = 0; i < len; ++i) P[colstart + i] = src[i];
    }
    __syncthreads();
    for (int i = t; i < cnt; i += 256) atomicAdd(&nh[P[i] & 255u], 1);
    __syncthreads();
    const int c = nh[t];
    const int nb_ex = excl_scan256(c, sc);
    nbx[t] = nb_ex;
    const int gnode = b * 256 + t;
    if (gnode < NN) { rowptr[gnode] = csrbase + nb_ex; deg[gnode] = c; }
    __syncthreads();
    for (int i = t; i < cnt; i += 256) {
        uint v = P[i];
        int l = (int)(v & 255u);
        int r = atomicAdd(&ncur[l], 1);
        csr_src[csrbase + nbx[l] + r] = (int)(v >> 8);
    }
}

// ---------------- layer 1 aggregate: masked batch-4, hw exp2, voffset gathers ----------------

__global__ __launch_bounds__(256) void k_agg1(const uint* __restrict__ xlh2,
                                              const uint* __restrict__ xrh2,
                                              const int* __restrict__ rowptr,
                                              const int* __restrict__ deg,
                                              const int* __restrict__ csr_src,
                                              const float* __restrict__ att1,
                                              const float* __restrict__ b1,
                                              uint* __restrict__ hbh2) {
    const int node = blockIdx.x * 4 + (threadIdx.x >> 6);
    if (node >= NN) return;
    const int lane = threadIdx.x & 63;
    const int fl = lane & 31;
    const uint fl4 = (uint)fl * 4u;
    const int hid = lane >> 5;
    float2 av = *(const float2*)&att1[2 * fl];
    U2H att; att.u = pkrtz_u(av.x * LOG2E, av.y * LOG2E);
    U2H xrf; xrf.u = xrh2[(size_t)node * 32 + fl];
    const int start = rowptr[node];
    const int dg = deg[node];
    const int permbase = (lane & 32) >> 3;

    float denom = 0.f, acc0 = 0.f, acc1 = 0.f;
    for (int base = 0; base < dg; base += 64) {
        int idx = base + lane;
        uint srcb = (idx < dg) ? ((uint)csr_src[start + idx] << 7) : 0u;  // row byte offset
        int rem = dg - base; if (rem > 64) rem = 64;
        int iters = (rem + 1) >> 1;
        int thr = (rem - hid + 1) >> 1;
        for (int jj = 0; jj < iters; jj += 4) {
            uint o0 = (uint)__builtin_amdgcn_ds_bpermute((jj + 0) * 8 + permbase, (int)srcb) + fl4;
            uint o1 = (uint)__builtin_amdgcn_ds_bpermute((jj + 1) * 8 + permbase, (int)srcb) + fl4;
            uint o2 = (uint)__builtin_amdgcn_ds_bpermute((jj + 2) * 8 + permbase, (int)srcb) + fl4;
            uint o3 = (uint)__builtin_amdgcn_ds_bpermute((jj + 3) * 8 + permbase, (int)srcb) + fl4;
            U2H v0; v0.u = ld_off(xlh2, o0);
            U2H v1; v1.u = ld_off(xlh2, o1);
            U2H v2; v2.u = ld_off(xlh2, o2);
            U2H v3; v3.u = ld_off(xlh2, o3);
            float t0 = red8(dot2f(lrelu2(v0.h + xrf.h), att.h, 0.f));
            float t1 = red8(dot2f(lrelu2(v1.h + xrf.h), att.h, 0.f));
            float t2 = red8(dot2f(lrelu2(v2.h + xrf.h), att.h, 0.f));
            float t3 = red8(dot2f(lrelu2(v3.h + xrf.h), att.h, 0.f));
            float e0 = (jj + 0 < thr) ? fexp2(t0) : 0.f;
            float e1 = (jj + 1 < thr) ? fexp2(t1) : 0.f;
            float e2 = (jj + 2 < thr) ? fexp2(t2) : 0.f;
            float e3 = (jj + 3 < thr) ? fexp2(t3) : 0.f;
            denom += (e0 + e1) + (e2 + e3);
            acc0 = fmaf(e0, (float)v0.h.x, acc0);
            acc0 = fmaf(e1, (float)v1.h.x, acc0);
            acc0 = fmaf(e2, (float)v2.h.x, acc0);
            acc0 = fmaf(e3, (float)v3.h.x, acc0);
            acc1 = fmaf(e0, (float)v0.h.y, acc1);
            acc1 = fmaf(e1, (float)v1.h.y, acc1);
            acc1 = fmaf(e2, (float)v2.h.y, acc1);
            acc1 = fmaf(e3, (float)v3.h.y, acc1);
        }
    }
    denom += __shfl_xor(denom, 32);
    acc0  += __shfl_xor(acc0, 32);
    acc1  += __shfl_xor(acc1, 32);
    if (lane < 32) {
        float r = (dg > 0) ? (1.0f / denom) : 0.f;
        float2 bv = *(const float2*)&b1[2 * fl];
        float o0 = fmaf(acc0, r, bv.x);
        float o1 = fmaf(acc1, r, bv.y);
        o0 = o0 > 0.f ? o0 : expm1f(o0);
        o1 = o1 > 0.f ? o1 : expm1f(o1);
        hbh2[(size_t)node * 32 + fl] = pkrtz_u(o0, o1);
    }
}

// ---------------- layer 2 GEMM: node per thread, packed half2 outputs ----------------

__global__ __launch_bounds__(256) void k_gemm2(const uint* __restrict__ hbh2,
                                               const float* __restrict__ W2l,
                                               const float* __restrict__ W2r,
                                               uint* __restrict__ xl2h,
                                               uint* __restrict__ xr2h) {
    int n = blockIdx.x * 256 + threadIdx.x;
    if (n >= NN) return;
    float al[NC] = {}, ar[NC] = {};
    const uint4* hr4 = (const uint4*)(hbh2 + (size_t)n * 32);
#pragma unroll
    for (int q = 0; q < 8; ++q) {
        uint4 qq = hr4[q];
        uint uu[4] = {qq.x, qq.y, qq.z, qq.w};
#pragma unroll
        for (int j = 0; j < 4; ++j) {
            U2H hh; hh.u = uu[j];
            float f0 = (float)hh.h.x, f1 = (float)hh.h.y;
            int k = q * 8 + j * 2;
            const float* wl0 = W2l + k * NC;
            const float* wr0 = W2r + k * NC;
#pragma unroll
            for (int c = 0; c < NC; ++c) {
                al[c] = fmaf(f0, wl0[c], fmaf(f1, wl0[NC + c], al[c]));
                ar[c] = fmaf(f0, wr0[c], fmaf(f1, wr0[NC + c], ar[c]));
            }
        }
    }
    uint p0 = pkrtz_u(al[0], al[1]);
    uint p1 = pkrtz_u(al[2], al[3]);
    uint p2 = pkrtz_u(al[4], al[5]);
    uint p3 = pkrtz_u(al[6], al[7]);
    uint p4 = pkrtz_u(al[8], al[9]);
    *(uint4*)&xl2h[(size_t)n * 8]     = make_uint4(p0, p1, p2, p3);
    *(uint4*)&xl2h[(size_t)n * 8 + 4] = make_uint4(p4, 0u, 0u, 0u);
    p0 = pkrtz_u(ar[0], ar[1]);
    p1 = pkrtz_u(ar[2], ar[3]);
    p2 = pkrtz_u(ar[4], ar[5]);
    p3 = pkrtz_u(ar[6], ar[7]);
    p4 = pkrtz_u(ar[8], ar[9]);
    *(uint4*)&xr2h[(size_t)n * 8]     = make_uint4(p0, p1, p2, p3);
    *(uint4*)&xr2h[(size_t)n * 8 + 4] = make_uint4(p4, 0u, 0u, 0u);
}

// ---------------- layer 2 aggregate: masked batch-4, hw exp2, voffset gathers ----------------

__global__ __launch_bounds__(256) void k_agg2(const uint* __restrict__ xl2h,
                                              const uint* __restrict__ xr2h,
                                              const int* __restrict__ rowptr,
                                              const int* __restrict__ deg,
                                              const int* __restrict__ csr_src,
                                              const float* __restrict__ att2,
                                              const float* __restrict__ b2,
                                              float* __restrict__ out) {
    const int node = blockIdx.x * 4 + (threadIdx.x >> 6);
    if (node >= NN) return;
    const int lane = threadIdx.x & 63;
    const int fp = lane & 7;
    const uint fp4 = (uint)fp * 4u;
    const int eg = lane >> 3;
    U2H att;
    if (fp < 5) {
        float2 av = *(const float2*)&att2[2 * fp];
        att.u = pkrtz_u(av.x * LOG2E, av.y * LOG2E);
    } else {
        att.u = 0;
    }
    U2H xrf; xrf.u = xr2h[(size_t)node * 8 + fp];
    const int start = rowptr[node];
    const int dg = deg[node];
    const int permbase = eg * 4;

    float denom = 0.f, acc0 = 0.f, acc1 = 0.f;
    for (int base = 0; base < dg; base += 64) {
        int idx = base + lane;
        uint srcb = (idx < dg) ? ((uint)csr_src[start + idx] << 5) : 0u;
        int rem = dg - base; if (rem > 64) rem = 64;
        int iters = (rem + 7) >> 3;
        int thr = (rem - eg + 7) >> 3;
        for (int jj = 0; jj < iters; jj += 4) {
            uint o[4]; U2H v[4];
#pragma unroll
            for (int k = 0; k < 4; ++k)
                o[k] = (uint)__builtin_amdgcn_ds_bpermute((jj + k) * 32 + permbase, (int)srcb) + fp4;
#pragma unroll
            for (int k = 0; k < 4; ++k)
                v[k].u = ld_off(xl2h, o[k]);
#pragma unroll
            for (int k = 0; k < 4; ++k) {
                float tl = red8(dot2f(lrelu2(v[k].h + xrf.h), att.h, 0.f));
                float e = (jj + k < thr) ? fexp2(tl) : 0.f;
                denom += e;
                acc0 = fmaf(e, (float)v[k].h.x, acc0);
                acc1 = fmaf(e, (float)v[k].h.y, acc1);
            }
        }
    }
#pragma unroll
    for (int m = 8; m <= 32; m <<= 1) {
        denom += __shfl_xor(denom, m);
        acc0  += __shfl_xor(acc0, m);
        acc1  += __shfl_xor(acc1, m);
    }
    if (lane < 5) {
        float r = (dg > 0) ? (1.0f / denom) : 0.f;
        float2 o;
        o.x = fmaf(acc0, r, b2[2 * fp]);
        o.y = fmaf(acc1, r, b2[2 * fp + 1]);
        *(float2*)&out[(size_t)node * NC + 2 * fp] = o;
    }
}

// ---------------- launch ----------------

extern "C" void kernel_launch(void* const* d_in, const int* in_sizes, int n_in,
                              void* d_out, int out_size, void* d_ws, size_t ws_size,
                              hipStream_t stream) {
    const float* x    = (const float*)d_in[0];
    const int*   ei   = (const int*)d_in[1];
    const float* W1l  = (const float*)d_in[2];
    const float* W1r  = (const float*)d_in[3];
    const float* att1 = (const float*)d_in[4];
    const float* b1   = (const float*)d_in[5];
    const float* W2l  = (const float*)d_in[6];
    const float* W2r  = (const float*)d_in[7];
    const float* att2 = (const float*)d_in[8];
    const float* b2   = (const float*)d_in[9];
    float* out = (float*)d_out;

    char* w = (char*)d_ws;
    size_t off = 0;
    auto alloc = [&](size_t bytes) -> void* {
        void* p = w + off;
        off = (off + bytes + 255) & ~(size_t)255;
        return p;
    };
    uint* xlh2   = (uint*)alloc((size_t)NN * 32 * 4);
    uint* xrh2   = (uint*)alloc((size_t)NN * 32 * 4);
    uint* hbh2   = (uint*)alloc((size_t)NN * 32 * 4);
    uint* xl2h   = (uint*)alloc((size_t)NN * 8 * 4);
    uint* xr2h   = (uint*)alloc((size_t)NN * 8 * 4);
    uint* temp   = (uint*)alloc((size_t)P1B * CHUNK * 4);
    int*  lbmat  = (int*)alloc((size_t)P1B * LBW * 4);
    int*  rowptr = (int*)alloc((size_t)NN * 4);
    int*  deg    = (int*)alloc((size_t)NN * 4);
    int*  csr_src = (int*)alloc((size_t)(NE + 64) * 4);

    k_fusedA<<<P1B + GMT, 256, 0, stream>>>(x, ei, W1l, W1r,
                                            (_Float16*)xlh2, (_Float16*)xrh2,
                                            temp, lbmat);
    k_pass2<<<NB, 256, 0, stream>>>(temp, lbmat, rowptr, deg, csr_src);
    k_agg1<<<(NN + 3) / 4, 256, 0, stream>>>(xlh2, xrh2, rowptr, deg, csr_src, att1, b1, hbh2);
    k_gemm2<<<(NN + 255) / 256, 256, 0, stream>>>(hbh2, W2l, W2r, xl2h, xr2h);
    k_agg2<<<(NN + 3) / 4, 256, 0, stream>>>(xl2h, xr2h, rowptr, deg, csr_src, att2, b2, out);
}